// Round 2
// baseline (2357.401 us; speedup 1.0000x reference)
//
#include <hip/hip_runtime.h>
#include <math.h>

// GCN: h1 = relu(GCNConv(x, W1, b1)); emb = GCNConv(h1, W2, b2);
// out = (emb@Wt+bt, emb@Ws+bs, emb@Wf+bf, emb@Wa+ba) concatenated flat.
// N=50000 nodes, C=128 channels everywhere, E=800000 edges, heads 30/20/15/2000.

#define CH 128

// ---------------- degree / normalization ----------------

__global__ void deg_init_kernel(float* __restrict__ deg, int n) {
    int i = blockIdx.x * blockDim.x + threadIdx.x;
    if (i < n) deg[i] = 1.0f;  // self loop contributes 1
}

__global__ void deg_count_kernel(const int* __restrict__ row, float* __restrict__ deg, int E) {
    int i = blockIdx.x * blockDim.x + threadIdx.x;
    if (i < E) atomicAdd(&deg[row[i]], 1.0f);
}

__global__ void dinv_kernel(float* __restrict__ deg, int n) {
    int i = blockIdx.x * blockDim.x + threadIdx.x;
    if (i < n) deg[i] = rsqrtf(fmaxf(deg[i], 1.0f));
}

// ---------------- generic fp32 GEMM, K=128 fixed ----------------
// C[M x N] = op(A)[M x 128] @ W[128 x N] (+ bias).  BM=BN=64, BK=64, 256 thr, 4x4/thread.
template<bool RELU_A, bool BIAS>
__launch_bounds__(256)
__global__ void gemm_k128(const float* __restrict__ A, const float* __restrict__ W,
                          const float* __restrict__ bias, float* __restrict__ Cout,
                          int M, int N) {
    __shared__ float As[64 * 65];  // k-major: As[k*65 + row], pad 65 kills write conflicts
    __shared__ float Bs[64 * 64];  // k-major: Bs[k*64 + col]

    const int tid = threadIdx.x;
    const int tx = tid & 15;        // col group
    const int ty = tid >> 4;        // row group
    const int rowBase = blockIdx.y * 64;
    const int colBase = blockIdx.x * 64;

    float acc[4][4] = {{0.f}};

    for (int kb = 0; kb < 128; kb += 64) {
        // A tile: 64 rows x 64 k, transposed into LDS (k-major)
#pragma unroll
        for (int l = 0; l < 4; ++l) {
            int idx = tid + l * 256;      // 0..1023
            int r   = idx >> 4;           // 0..63
            int c4  = idx & 15;           // 0..15 (k/4)
            int grow = rowBase + r;
            float4 v = make_float4(0.f, 0.f, 0.f, 0.f);
            if (grow < M)
                v = *(const float4*)(A + (size_t)grow * CH + kb + c4 * 4);
            if (RELU_A) {
                v.x = fmaxf(v.x, 0.f); v.y = fmaxf(v.y, 0.f);
                v.z = fmaxf(v.z, 0.f); v.w = fmaxf(v.w, 0.f);
            }
            As[(c4 * 4 + 0) * 65 + r] = v.x;
            As[(c4 * 4 + 1) * 65 + r] = v.y;
            As[(c4 * 4 + 2) * 65 + r] = v.z;
            As[(c4 * 4 + 3) * 65 + r] = v.w;
        }
        // B tile: 64 k x 64 cols, natural layout
#pragma unroll
        for (int l = 0; l < 4; ++l) {
            int idx = tid + l * 256;
            int k   = idx >> 4;
            int c4  = idx & 15;
            int gcol = colBase + c4 * 4;
            float4 v = make_float4(0.f, 0.f, 0.f, 0.f);
            if (((N & 3) == 0) && (gcol + 3 < N)) {
                v = *(const float4*)(W + (size_t)(kb + k) * N + gcol);
            } else {
                float* pv = (float*)&v;
#pragma unroll
                for (int t = 0; t < 4; ++t)
                    if (gcol + t < N) pv[t] = W[(size_t)(kb + k) * N + gcol + t];
            }
            *(float4*)(Bs + k * 64 + c4 * 4) = v;
        }
        __syncthreads();

#pragma unroll
        for (int k = 0; k < 64; ++k) {
            float4 b4 = *(const float4*)(Bs + k * 64 + tx * 4);
            float a0 = As[k * 65 + ty * 4 + 0];
            float a1 = As[k * 65 + ty * 4 + 1];
            float a2 = As[k * 65 + ty * 4 + 2];
            float a3 = As[k * 65 + ty * 4 + 3];
            acc[0][0] += a0 * b4.x; acc[0][1] += a0 * b4.y; acc[0][2] += a0 * b4.z; acc[0][3] += a0 * b4.w;
            acc[1][0] += a1 * b4.x; acc[1][1] += a1 * b4.y; acc[1][2] += a1 * b4.z; acc[1][3] += a1 * b4.w;
            acc[2][0] += a2 * b4.x; acc[2][1] += a2 * b4.y; acc[2][2] += a2 * b4.z; acc[2][3] += a2 * b4.w;
            acc[3][0] += a3 * b4.x; acc[3][1] += a3 * b4.y; acc[3][2] += a3 * b4.z; acc[3][3] += a3 * b4.w;
        }
        __syncthreads();
    }

#pragma unroll
    for (int i = 0; i < 4; ++i) {
        int grow = rowBase + ty * 4 + i;
        if (grow >= M) continue;
#pragma unroll
        for (int j = 0; j < 4; ++j) {
            int gcol = colBase + tx * 4 + j;
            if (gcol >= N) continue;
            float v = acc[i][j];
            if (BIAS) v += bias[gcol];
            Cout[(size_t)grow * N + gcol] = v;
        }
    }
}

// ---------------- propagation ----------------
// out[i][:] = tmp[i][:] * dinv[i]^2 + b[:]   (self-loop term + bias)
__global__ void prop_init_kernel(const float* __restrict__ tmp, const float* __restrict__ dinv,
                                 const float* __restrict__ bias, float* __restrict__ out, int n) {
    int idx = blockIdx.x * blockDim.x + threadIdx.x;
    if (idx >= n * 32) return;
    int node = idx >> 5;
    int c4   = idx & 31;
    float di = dinv[node];
    float s  = di * di;
    float4 v = *(const float4*)(tmp + (size_t)node * CH + c4 * 4);
    float4 b = *(const float4*)(bias + c4 * 4);
    float4 o;
    o.x = v.x * s + b.x; o.y = v.y * s + b.y;
    o.z = v.z * s + b.z; o.w = v.w * s + b.w;
    *(float4*)(out + (size_t)node * CH + c4 * 4) = o;
}

// out[row][:] += tmp[col][:] * dinv[row]*dinv[col]   for each edge (wave per edge)
__launch_bounds__(256)
__global__ void prop_scatter_kernel(const float* __restrict__ tmp, const float* __restrict__ dinv,
                                    const int* __restrict__ ei, float* __restrict__ out, int E) {
    int lane   = threadIdx.x & 63;
    int wave   = blockIdx.x * (blockDim.x >> 6) + (threadIdx.x >> 6);
    int nwaves = gridDim.x * (blockDim.x >> 6);
    for (int e = wave; e < E; e += nwaves) {
        int r = ei[e];          // destination (segment_sum over row)
        int c = ei[E + e];      // source (gather h[col])
        float norm = dinv[r] * dinv[c];
        float2 v = *(const float2*)(tmp + (size_t)c * CH + lane * 2);
        atomicAdd(out + (size_t)r * CH + lane * 2 + 0, v.x * norm);
        atomicAdd(out + (size_t)r * CH + lane * 2 + 1, v.y * norm);
    }
}

// ---------------- launch ----------------

extern "C" void kernel_launch(void* const* d_in, const int* in_sizes, int n_in,
                              void* d_out, int out_size, void* d_ws, size_t ws_size,
                              hipStream_t stream) {
    const float* x  = (const float*)d_in[0];
    const int*   ei = (const int*)d_in[1];
    const float* W1 = (const float*)d_in[2];
    const float* b1 = (const float*)d_in[3];
    const float* W2 = (const float*)d_in[4];
    const float* b2 = (const float*)d_in[5];
    const float* Wt = (const float*)d_in[6];
    const float* bt = (const float*)d_in[7];
    const float* Ws = (const float*)d_in[8];
    const float* bs = (const float*)d_in[9];
    const float* Wf = (const float*)d_in[10];
    const float* bf = (const float*)d_in[11];
    const float* Wa = (const float*)d_in[12];
    const float* ba = (const float*)d_in[13];

    const int N = in_sizes[0] / CH;   // 50000
    const int E = in_sizes[1] / 2;    // 800000
    float* out = (float*)d_out;

    float* ws_f = (float*)d_ws;
    float* deg  = ws_f;                           // N floats (becomes dinv in place)
    float* buf1 = ws_f + 50176;                   // N*128, 50176 = 196*256 >= N, keeps float4 alignment
    float* buf2 = buf1 + (size_t)N * CH;          // N*128

    const int nodeBlocks = (N + 255) / 256;
    const int rowBlocks  = (N + 63) / 64;

    // normalization
    deg_init_kernel<<<nodeBlocks, 256, 0, stream>>>(deg, N);
    deg_count_kernel<<<(E + 255) / 256, 256, 0, stream>>>(ei, deg, E);
    dinv_kernel<<<nodeBlocks, 256, 0, stream>>>(deg, N);

    // layer 1: buf1 = x @ W1 ; buf2 = propagate(buf1) + b1
    gemm_k128<false, false><<<dim3(2, rowBlocks), 256, 0, stream>>>(x, W1, nullptr, buf1, N, CH);
    prop_init_kernel<<<(N * 32 + 255) / 256, 256, 0, stream>>>(buf1, deg, b1, buf2, N);
    prop_scatter_kernel<<<4096, 256, 0, stream>>>(buf1, deg, ei, buf2, E);

    // layer 2: buf1 = relu(buf2) @ W2 ; buf2 = propagate(buf1) + b2  (emb)
    gemm_k128<true, false><<<dim3(2, rowBlocks), 256, 0, stream>>>(buf2, W2, nullptr, buf1, N, CH);
    prop_init_kernel<<<(N * 32 + 255) / 256, 256, 0, stream>>>(buf1, deg, b2, buf2, N);
    prop_scatter_kernel<<<4096, 256, 0, stream>>>(buf1, deg, ei, buf2, E);

    // heads (emb = buf2)
    float* out_t = out;
    float* out_s = out_t + (size_t)N * 30;
    float* out_f = out_s + (size_t)N * 20;
    float* out_a = out_f + (size_t)N * 15;
    gemm_k128<false, true><<<dim3(1,  rowBlocks), 256, 0, stream>>>(buf2, Wt, bt, out_t, N, 30);
    gemm_k128<false, true><<<dim3(1,  rowBlocks), 256, 0, stream>>>(buf2, Ws, bs, out_s, N, 20);
    gemm_k128<false, true><<<dim3(1,  rowBlocks), 256, 0, stream>>>(buf2, Wf, bf, out_f, N, 15);
    gemm_k128<false, true><<<dim3(32, rowBlocks), 256, 0, stream>>>(buf2, Wa, ba, out_a, N, 2000);
}

// Round 3
// 1254.801 us; speedup vs baseline: 1.8787x; 1.8787x over previous
//
#include <hip/hip_runtime.h>
#include <math.h>

// GCN: h1 = relu(GCNConv(x, W1, b1)); emb = GCNConv(h1, W2, b2);
// out = (emb@Wt+bt, emb@Ws+bs, emb@Wf+bf, emb@Wa+ba) concatenated flat.
// N=50000 nodes, C=128 channels, E=800000 edges, heads 30/20/15/2000.
//
// R2 change: atomic scatter (800MB HBM atomic write-through, 2x655us) replaced by
// device-built CSR + gather-per-node aggregation. GEMM epilogue pre-scales rows by
// dinv so aggregation is out[r] = dinv[r]*(ts[r] + sum ts[c]) + b.

#define CH 128

// ---------------- CSR build ----------------

__global__ void zero_int_kernel(int* __restrict__ p, int n) {
    int i = blockIdx.x * blockDim.x + threadIdx.x;
    if (i < n) p[i] = 0;
}

__global__ void deg_count_kernel(const int* __restrict__ row, int* __restrict__ degint, int E) {
    int i = blockIdx.x * blockDim.x + threadIdx.x;
    if (i < E) atomicAdd(&degint[row[i]], 1);
}

// dinv[i] = rsqrt(deg_with_selfloop) = rsqrt(degint[i] + 1)
__global__ void dinv_kernel(const int* __restrict__ degint, float* __restrict__ dinv, int n) {
    int i = blockIdx.x * blockDim.x + threadIdx.x;
    if (i < n) dinv[i] = rsqrtf((float)(degint[i] + 1));
}

// Single-workgroup chunked exclusive scan: offs[0..n] from degint[0..n-1].
#define SCAN_T 1024
#define SCAN_E 8
__launch_bounds__(SCAN_T)
__global__ void scan_kernel(const int* __restrict__ degint, int* __restrict__ offs, int n) {
    __shared__ int sdata[SCAN_T];
    __shared__ int carry_s;
    const int tid = threadIdx.x;
    if (tid == 0) carry_s = 0;
    __syncthreads();
    for (int base = 0; base < n; base += SCAN_T * SCAN_E) {
        int loc[SCAN_E];
        const int i0 = base + tid * SCAN_E;
        int s = 0;
#pragma unroll
        for (int j = 0; j < SCAN_E; ++j) {
            int i = i0 + j;
            loc[j] = (i < n) ? degint[i] : 0;
            s += loc[j];
        }
        sdata[tid] = s;
        __syncthreads();
        for (int off = 1; off < SCAN_T; off <<= 1) {
            int t = (tid >= off) ? sdata[tid - off] : 0;
            __syncthreads();
            sdata[tid] += t;
            __syncthreads();
        }
        int excl = carry_s + sdata[tid] - s;  // exclusive prefix of this thread's first elem
#pragma unroll
        for (int j = 0; j < SCAN_E; ++j) {
            int i = i0 + j;
            if (i < n) offs[i] = excl;
            excl += loc[j];
        }
        __syncthreads();                      // all carry_s reads done
        if (tid == SCAN_T - 1) carry_s = excl;
        __syncthreads();
    }
    if (tid == 0) offs[n] = carry_s;
}

__global__ void fill_kernel(const int* __restrict__ ei, const int* __restrict__ offs,
                            int* __restrict__ cnt, int* __restrict__ adj, int E) {
    int e = blockIdx.x * blockDim.x + threadIdx.x;
    if (e < E) {
        int r = ei[e];
        int c = ei[E + e];
        int p = offs[r] + atomicAdd(&cnt[r], 1);
        adj[p] = c;
    }
}

// ---------------- fp32 GEMM, K=128 fixed ----------------
// C[M x N] = op(A)[M x 128] @ W[128 x N]; epilogue: optional bias add OR row-scale by dinv.
template<bool RELU_A, bool BIAS, bool SCALE_DINV>
__launch_bounds__(256)
__global__ void gemm_k128(const float* __restrict__ A, const float* __restrict__ W,
                          const float* __restrict__ bias, const float* __restrict__ dinv,
                          float* __restrict__ Cout, int M, int N) {
    __shared__ float As[64 * 65];  // k-major: As[k*65 + row]
    __shared__ float Bs[64 * 64];  // k-major: Bs[k*64 + col]

    const int tid = threadIdx.x;
    const int tx = tid & 15;
    const int ty = tid >> 4;
    const int rowBase = blockIdx.y * 64;
    const int colBase = blockIdx.x * 64;

    float acc[4][4] = {{0.f}};

    for (int kb = 0; kb < 128; kb += 64) {
#pragma unroll
        for (int l = 0; l < 4; ++l) {
            int idx = tid + l * 256;
            int r   = idx >> 4;
            int c4  = idx & 15;
            int grow = rowBase + r;
            float4 v = make_float4(0.f, 0.f, 0.f, 0.f);
            if (grow < M)
                v = *(const float4*)(A + (size_t)grow * CH + kb + c4 * 4);
            if (RELU_A) {
                v.x = fmaxf(v.x, 0.f); v.y = fmaxf(v.y, 0.f);
                v.z = fmaxf(v.z, 0.f); v.w = fmaxf(v.w, 0.f);
            }
            As[(c4 * 4 + 0) * 65 + r] = v.x;
            As[(c4 * 4 + 1) * 65 + r] = v.y;
            As[(c4 * 4 + 2) * 65 + r] = v.z;
            As[(c4 * 4 + 3) * 65 + r] = v.w;
        }
#pragma unroll
        for (int l = 0; l < 4; ++l) {
            int idx = tid + l * 256;
            int k   = idx >> 4;
            int c4  = idx & 15;
            int gcol = colBase + c4 * 4;
            float4 v = make_float4(0.f, 0.f, 0.f, 0.f);
            if (((N & 3) == 0) && (gcol + 3 < N)) {
                v = *(const float4*)(W + (size_t)(kb + k) * N + gcol);
            } else {
                float* pv = (float*)&v;
#pragma unroll
                for (int t = 0; t < 4; ++t)
                    if (gcol + t < N) pv[t] = W[(size_t)(kb + k) * N + gcol + t];
            }
            *(float4*)(Bs + k * 64 + c4 * 4) = v;
        }
        __syncthreads();

#pragma unroll
        for (int k = 0; k < 64; ++k) {
            float4 b4 = *(const float4*)(Bs + k * 64 + tx * 4);
            float a0 = As[k * 65 + ty * 4 + 0];
            float a1 = As[k * 65 + ty * 4 + 1];
            float a2 = As[k * 65 + ty * 4 + 2];
            float a3 = As[k * 65 + ty * 4 + 3];
            acc[0][0] += a0 * b4.x; acc[0][1] += a0 * b4.y; acc[0][2] += a0 * b4.z; acc[0][3] += a0 * b4.w;
            acc[1][0] += a1 * b4.x; acc[1][1] += a1 * b4.y; acc[1][2] += a1 * b4.z; acc[1][3] += a1 * b4.w;
            acc[2][0] += a2 * b4.x; acc[2][1] += a2 * b4.y; acc[2][2] += a2 * b4.z; acc[2][3] += a2 * b4.w;
            acc[3][0] += a3 * b4.x; acc[3][1] += a3 * b4.y; acc[3][2] += a3 * b4.z; acc[3][3] += a3 * b4.w;
        }
        __syncthreads();
    }

#pragma unroll
    for (int i = 0; i < 4; ++i) {
        int grow = rowBase + ty * 4 + i;
        if (grow >= M) continue;
        float rs = SCALE_DINV ? dinv[grow] : 1.0f;
#pragma unroll
        for (int j = 0; j < 4; ++j) {
            int gcol = colBase + tx * 4 + j;
            if (gcol >= N) continue;
            float v = acc[i][j];
            if (SCALE_DINV) v *= rs;
            if (BIAS) v += bias[gcol];
            Cout[(size_t)grow * N + gcol] = v;
        }
    }
}

// ---------------- aggregation: wave per node ----------------
// out[r][:] = dinv[r] * (ts[r][:] + sum_{c in N(r)} ts[c][:]) + bias[:]
__launch_bounds__(256)
__global__ void aggregate_kernel(const float* __restrict__ ts, const float* __restrict__ dinv,
                                 const int* __restrict__ offs, const int* __restrict__ adj,
                                 const float* __restrict__ bias, float* __restrict__ out, int n) {
    const int lane = threadIdx.x & 63;
    const int node = blockIdx.x * 4 + (threadIdx.x >> 6);
    if (node >= n) return;
    const int beg = offs[node];
    const int end = offs[node + 1];
    float2 acc = *(const float2*)(ts + (size_t)node * CH + lane * 2);  // self-loop term
    for (int p = beg; p < end; ++p) {
        int c = adj[p];
        float2 v = *(const float2*)(ts + (size_t)c * CH + lane * 2);
        acc.x += v.x;
        acc.y += v.y;
    }
    const float dr = dinv[node];
    float2 b = *(const float2*)(bias + lane * 2);
    float2 o;
    o.x = acc.x * dr + b.x;
    o.y = acc.y * dr + b.y;
    *(float2*)(out + (size_t)node * CH + lane * 2) = o;
}

// ---------------- launch ----------------

extern "C" void kernel_launch(void* const* d_in, const int* in_sizes, int n_in,
                              void* d_out, int out_size, void* d_ws, size_t ws_size,
                              hipStream_t stream) {
    const float* x  = (const float*)d_in[0];
    const int*   ei = (const int*)d_in[1];
    const float* W1 = (const float*)d_in[2];
    const float* b1 = (const float*)d_in[3];
    const float* W2 = (const float*)d_in[4];
    const float* b2 = (const float*)d_in[5];
    const float* Wt = (const float*)d_in[6];
    const float* bt = (const float*)d_in[7];
    const float* Ws = (const float*)d_in[8];
    const float* bs = (const float*)d_in[9];
    const float* Wf = (const float*)d_in[10];
    const float* bf = (const float*)d_in[11];
    const float* Wa = (const float*)d_in[12];
    const float* ba = (const float*)d_in[13];

    const int N = in_sizes[0] / CH;   // 50000
    const int E = in_sizes[1] / 2;    // 800000
    float* out = (float*)d_out;

    // ws layout (floats): dinv[50176] | offs(int)[50304] | adj(int)[800256] | buf1[N*CH] | buf2[N*CH]
    float* ws_f  = (float*)d_ws;
    float* dinv  = ws_f;
    int*   offs  = (int*)(ws_f + 50176);
    int*   adj   = (int*)(ws_f + 50176 + 50304);
    float* buf1  = ws_f + 50176 + 50304 + 800256;
    float* buf2  = buf1 + (size_t)N * CH;
    // aliases (lifetimes don't overlap):
    int* degint = (int*)buf1;  // consumed by scan/dinv before GEMM1 writes buf1
    int* cnt    = (int*)buf2;  // consumed by fill before aggregate writes buf2

    const int nodeBlocks = (N + 255) / 256;
    const int rowBlocks  = (N + 63) / 64;
    const int aggBlocks  = (N + 3) / 4;

    // CSR build
    zero_int_kernel<<<nodeBlocks, 256, 0, stream>>>(degint, N);
    zero_int_kernel<<<nodeBlocks, 256, 0, stream>>>(cnt, N);
    deg_count_kernel<<<(E + 255) / 256, 256, 0, stream>>>(ei, degint, E);
    dinv_kernel<<<nodeBlocks, 256, 0, stream>>>(degint, dinv, N);
    scan_kernel<<<1, SCAN_T, 0, stream>>>(degint, offs, N);
    fill_kernel<<<(E + 255) / 256, 256, 0, stream>>>(ei, offs, cnt, adj, E);

    // layer 1: buf1 = (x @ W1) * dinv[row] ; buf2 = aggregate(buf1) + b1
    gemm_k128<false, false, true><<<dim3(2, rowBlocks), 256, 0, stream>>>(x, W1, nullptr, dinv, buf1, N, CH);
    aggregate_kernel<<<aggBlocks, 256, 0, stream>>>(buf1, dinv, offs, adj, b1, buf2, N);

    // layer 2: buf1 = (relu(buf2) @ W2) * dinv[row] ; buf2 = aggregate(buf1) + b2 = emb
    gemm_k128<true, false, true><<<dim3(2, rowBlocks), 256, 0, stream>>>(buf2, W2, nullptr, dinv, buf1, N, CH);
    aggregate_kernel<<<aggBlocks, 256, 0, stream>>>(buf1, dinv, offs, adj, b2, buf2, N);

    // heads (emb = buf2)
    float* out_t = out;
    float* out_s = out_t + (size_t)N * 30;
    float* out_f = out_s + (size_t)N * 20;
    float* out_a = out_f + (size_t)N * 15;
    gemm_k128<false, true, false><<<dim3(1,  rowBlocks), 256, 0, stream>>>(buf2, Wt, bt, nullptr, out_t, N, 30);
    gemm_k128<false, true, false><<<dim3(1,  rowBlocks), 256, 0, stream>>>(buf2, Ws, bs, nullptr, out_s, N, 20);
    gemm_k128<false, true, false><<<dim3(1,  rowBlocks), 256, 0, stream>>>(buf2, Wf, bf, nullptr, out_f, N, 15);
    gemm_k128<false, true, false><<<dim3(32, rowBlocks), 256, 0, stream>>>(buf2, Wa, ba, nullptr, out_a, N, 2000);
}